// Round 7
// baseline (73.530 us; speedup 1.0000x reference)
//
#include <hip/hip_runtime.h>

// Polyphase resample up=3 down=2, N=2097152, L=129 taps, start=(L-1)/2=64.
// out[3j+0] = 3 * sum_i x[21+2j-i] * h[1+3i]   (i in [0,43))
// out[3j+1] = 3 * sum_i x[22+2j-i] * h[0+3i]
// out[3j+2] = 3 * sum_i x[22+2j-i] * h[2+3i]
// (formula verified across R0-R8, absmax 0.25)
//
// R9: R7(drains 6->3) and R8(occupancy 4->8 waves) were both NULL => kernel
// is issue/throughput-bound, not latency-bound. The padded-LDS layout forces
// ~54 ds_read_b32 (5.8cy, 44 B/cy) + 4 ds_write_b32 per thread + pad VALU.
// Unpadded layout: per-thread window base 4*tid+D is 16B-alignable =>
// 6x ds_read_b128 per chunk (85 B/cy, contiguous-per-lane = conflict-free
// canonical pattern) and 1x ds_write_b128 per staged float4. ~59 scalar LDS
// ops -> ~18 vector ops, pad arithmetic gone.
// COMPILER LAW kept (R3/R6 spills vs R0/R7 clean): chunks behind
// #pragma unroll 1; sched_barrier(0) fences the tail chunk so its b128s
// can't hoist over the loop. Per-chunk live: vec 24 + acc 6 + addr ~40 < 64.

#define N_SIG   2097152
#define L_FILT  129
#define NTAPS   43
#define G       2            // output groups per thread (6 outputs)
#define BLK     256
#define GROUPS_PER_BLK (BLK * G)             // 512 groups -> 1536 outputs/block
#define TILE_Q  1088                         // 272 float4s; covers q in [0,1088) ⊇ [3,1067]

// One tap-chunk of U taps starting at runtime i0. D = 45-(i0+U-1); RP = D&3
// must be compile-time so unpack indices are immediates. Window = U+2G-1
// words at q = 4*tid + D + k; read as NW aligned float4s from base
// 4*tid + (D-RP) (byte addr 16*tid + 4*(D-RP), 16B-aligned).
template <int U, int RP>
__device__ __forceinline__ void do_chunk(const float* __restrict__ xs,
                                         const float* __restrict__ h,
                                         int i0, int tid, float (&acc)[3 * G]) {
    const int D = 45 - (i0 + U - 1);                    // D & 3 == RP
    constexpr int NW = (RP + U + 2 * G - 1 + 3) >> 2;   // b128 count
    const float* base = xs + 4 * tid + (D - RP);
    float4 vec[NW];
#pragma unroll
    for (int m = 0; m < NW; ++m)
        vec[m] = *(const float4*)(base + 4 * m);        // ds_read_b128
    const float* vf = (const float*)vec;                // const-index unpack (SROA)
#pragma unroll
    for (int u = 0; u < U; ++u) {
        // wave-uniform indices -> scalar loads, SGPR operands in the FMAs
        const float h0 = h[3 * (i0 + u) + 0];
        const float h1 = h[3 * (i0 + u) + 1];
        const float h2 = h[3 * (i0 + u) + 2];
#pragma unroll
        for (int g = 0; g < G; ++g) {
            const float xa = vf[RP + (U - 1 - u) + 2 * g];      // x[21+2j-i]
            const float xb = vf[RP + (U - 1 - u) + 2 * g + 1];  // x[22+2j-i]
            acc[3 * g + 0] += xa * h1;
            acc[3 * g + 1] += xb * h0;
            acc[3 * g + 2] += xb * h2;
        }
    }
}

__global__ __launch_bounds__(BLK, 8) void poly_kernel(
    const float* __restrict__ x, const float* __restrict__ h,
    float* __restrict__ out, int n_out)
{
    __shared__ float xs[TILE_Q];

    const int tid = threadIdx.x;
    const int b   = blockIdx.x;

    // Tile base: local group jl uses x[2*GPB*b + {21,22} + 2*jl - i];
    // tb puts needed words at q = {45,46} + 2*jl - i in [3, 1067].
    const int tb = 2 * GROUPS_PER_BLK * b - 24;

    // Coalesced staging with zero-pad at edges; unpadded LDS, one
    // ds_write_b128 per float4.
    for (int q4 = tid; q4 < TILE_Q / 4; q4 += BLK) {
        const int gx = tb + 4 * q4;
        float4 v;
        if (gx >= 0 && gx + 3 < N_SIG) {
            v = *(const float4*)(x + gx);
        } else {
            v.x = (gx     >= 0 && gx     < N_SIG) ? x[gx]     : 0.0f;
            v.y = (gx + 1 >= 0 && gx + 1 < N_SIG) ? x[gx + 1] : 0.0f;
            v.z = (gx + 2 >= 0 && gx + 2 < N_SIG) ? x[gx + 2] : 0.0f;
            v.w = (gx + 3 >= 0 && gx + 3 < N_SIG) ? x[gx + 3] : 0.0f;
        }
        *(float4*)(xs + 4 * q4) = v;                    // ds_write_b128
    }
    __syncthreads();

    float acc[3 * G];
#pragma unroll
    for (int k = 0; k < 3 * G; ++k) acc[k] = 0.0f;

    // 2 chunks of 16 taps (D = 30, 14; D&3 == 2) behind the opaque backedge,
    // then the U=11 tail (D = 3, D&3 == 3) fenced so its reads can't hoist.
#pragma unroll 1
    for (int i0 = 0; i0 < 32; i0 += 16)
        do_chunk<16, 2>(xs, h, i0, tid, acc);
    __builtin_amdgcn_sched_barrier(0);
    do_chunk<11, 3>(xs, h, 32, tid, acc);

    // 6 contiguous outputs per thread; 3x float2 (8B-aligned, coalesced).
    // Fold the up=3 gain here.
    const int ob = 3 * GROUPS_PER_BLK * b + 3 * G * tid;
#pragma unroll
    for (int k = 0; k < 3; ++k) {
        if (ob + 2 * k + 1 < n_out) {
            *(float2*)(out + ob + 2 * k) =
                make_float2(3.0f * acc[2 * k + 0], 3.0f * acc[2 * k + 1]);
        }
    }
}

extern "C" void kernel_launch(void* const* d_in, const int* in_sizes, int n_in,
                              void* d_out, int out_size, void* d_ws, size_t ws_size,
                              hipStream_t stream) {
    const float* x = (const float*)d_in[0];
    const float* h = (const float*)d_in[1];
    float* out = (float*)d_out;
    const int blocks = (out_size + 3 * GROUPS_PER_BLK - 1) / (3 * GROUPS_PER_BLK);
    poly_kernel<<<blocks, BLK, 0, stream>>>(x, h, out, out_size);
}